// Round 12
// baseline (263.649 us; speedup 1.0000x reference)
//
#include <hip/hip_runtime.h>
#include <hip/hip_bf16.h>
#include <math.h>

// Problem constants
#define TT    2048
#define HH    8
#define RDIM  32
#define BB    2

typedef float  f4  __attribute__((ext_vector_type(4)));
typedef int    i4  __attribute__((ext_vector_type(4)));
typedef uint   u2  __attribute__((ext_vector_type(2)));
typedef uint   u4  __attribute__((ext_vector_type(4)));
typedef short  s8v __attribute__((ext_vector_type(8)));   // 8 x bf16 bits (4 VGPR)

// round-to-nearest f32 -> bf16 bits
__device__ __forceinline__ uint rnd16(float x) {
    return (__float_as_uint(x) + 0x8000u) >> 16;
}

union v8cast { u4 u; s8v s; };

// ---------------------------------------------------------------------------
// Kernel 0: Wt prep — transpose (Wq|Wk)[1024][256+256] f32 -> Wt[512][1024]
// bf16 (Wt[n][k] = W[k][n]). LDS-tiled 64x64. 1 MB output, L2-resident.
// ---------------------------------------------------------------------------
__global__ __launch_bounds__(256) void wt_prep(
    const float* __restrict__ Wq,
    const float* __restrict__ Wk,
    ushort* __restrict__ Wt)
{
    __shared__ float T[64][68];
    const int k0 = blockIdx.x * 64;
    const int n0 = blockIdx.y * 64;
    const float* W = (n0 < 256) ? Wq : Wk;
    const int nloc = n0 & 255;
    const int tid = threadIdx.x;

    #pragma unroll
    for (int r = 0; r < 4; ++r) {
        int kl  = (tid >> 4) + r * 16;
        int nl4 = (tid & 15) * 4;
        f4 v = *(const f4*)&W[(size_t)(k0 + kl) * 256 + nloc + nl4];
        T[nl4 + 0][kl] = v.x;
        T[nl4 + 1][kl] = v.y;
        T[nl4 + 2][kl] = v.z;
        T[nl4 + 3][kl] = v.w;
    }
    __syncthreads();

    const int nl = tid >> 2;
    const int kq = (tid & 3) * 16;
    u4 o0, o1;
    #pragma unroll
    for (int j = 0; j < 4; ++j) {
        uint lo = rnd16(T[nl][kq + 2 * j]);
        uint hi = rnd16(T[nl][kq + 2 * j + 1]);
        ((uint*)&o0)[j] = (hi << 16) | lo;
    }
    #pragma unroll
    for (int j = 0; j < 4; ++j) {
        uint lo = rnd16(T[nl][kq + 8 + 2 * j]);
        uint hi = rnd16(T[nl][kq + 8 + 2 * j + 1]);
        ((uint*)&o1)[j] = (hi << 16) | lo;
    }
    ushort* dst = Wt + (size_t)(n0 + nl) * 1024 + k0 + kq;
    *(u4*)dst = o0;
    *(u4*)(dst + 8) = o1;
}

// ---------------------------------------------------------------------------
// Kernel 1: MFMA projection.  sq/sk[m][n] = sum_k x[m][k] * Wt[n][k]
// mfma(A=Wt_tile, B=x_tile): D lane owns col m = lane&15, 4 consecutive n.
// ---------------------------------------------------------------------------
__global__ __launch_bounds__(256) void proj_mfma(
    const float* __restrict__ x,       // [4096][1024] f32
    const ushort* __restrict__ Wt,     // [512][1024] bf16 bits
    ushort* __restrict__ sqb,          // [4096][256] bf16 bits
    ushort* __restrict__ skb)          // [4096][256] bf16 bits
{
    const int tid = threadIdx.x;
    const int l   = tid & 63;
    const int w   = __builtin_amdgcn_readfirstlane(tid) >> 6;  // 0..3
    const int cl  = l & 15;
    const int g4  = l >> 4;
    const int m0  = (blockIdx.x * 4 + w) * 16;   // m-tile
    const int n0  = blockIdx.y * 64;             // n-block (64 wide)

    f4 acc0 = {0,0,0,0}, acc1 = {0,0,0,0}, acc2 = {0,0,0,0}, acc3 = {0,0,0,0};

    const float*  xrow = x + (size_t)(m0 + cl) * 1024;
    const ushort* wbase = Wt + (size_t)(n0 + cl) * 1024;

    for (int ks = 0; ks < 32; ++ks) {
        const int k = ks * 32 + g4 * 8;
        f4 xa = *(const f4*)&xrow[k];
        f4 xb2 = *(const f4*)&xrow[k + 4];
        v8cast bf;
        ((uint*)&bf.u)[0] = (rnd16(xa.y) << 16) | rnd16(xa.x);
        ((uint*)&bf.u)[1] = (rnd16(xa.w) << 16) | rnd16(xa.z);
        ((uint*)&bf.u)[2] = (rnd16(xb2.y) << 16) | rnd16(xb2.x);
        ((uint*)&bf.u)[3] = (rnd16(xb2.w) << 16) | rnd16(xb2.z);
        s8v a0 = *(const s8v*)(wbase + 0 * 16 * 1024 + k);
        s8v a1 = *(const s8v*)(wbase + 1 * 16 * 1024 + k);
        s8v a2 = *(const s8v*)(wbase + 2 * 16 * 1024 + k);
        s8v a3 = *(const s8v*)(wbase + 3 * 16 * 1024 + k);
        acc0 = __builtin_amdgcn_mfma_f32_16x16x32_bf16(a0, bf.s, acc0, 0, 0, 0);
        acc1 = __builtin_amdgcn_mfma_f32_16x16x32_bf16(a1, bf.s, acc1, 0, 0, 0);
        acc2 = __builtin_amdgcn_mfma_f32_16x16x32_bf16(a2, bf.s, acc2, 0, 0, 0);
        acc3 = __builtin_amdgcn_mfma_f32_16x16x32_bf16(a3, bf.s, acc3, 0, 0, 0);
    }

    const int m = m0 + cl;
    const int nbase = n0 + g4 * 4;
    ushort* obase = (n0 < 256) ? (sqb + (size_t)m * 256 + nbase)
                               : (skb + (size_t)m * 256 + (nbase - 256));
    f4 accs[4] = {acc0, acc1, acc2, acc3};
    #pragma unroll
    for (int t = 0; t < 4; ++t) {
        u2 pk;
        pk.x = (rnd16(accs[t][1]) << 16) | rnd16(accs[t][0]);
        pk.y = (rnd16(accs[t][3]) << 16) | rnd16(accs[t][2]);
        *(u2*)(obase + t * 16) = pk;
    }
}

// ---------------------------------------------------------------------------
// Kernel 2: MFMA scores + mask + gumbel + softmax (swapped operands),
// SOFTWARE-PIPELINED: per half, prefetch ALL 8 tiles' operands into
// registers before computing.
//  - __launch_bounds__(1024,4): VGPR cap 128 (R11's compiler chose 48 ->
//    per-wave MLP ~1-2 outstanding loads; THAT was the serializer)
//  - sk A-frags (L2-fast) issued FIRST so their vmcnt waits don't drain the
//    HBM gumbel/mask loads behind them (vmcnt is FIFO)
//  - then 8x gumbel f4 + 8x mask i4 (HBM, ~900cy) -> 16 loads in flight
//    per wave; 16 waves/CU -> ~256KB in flight per CU (Little's law: >>
//    enough to saturate HBM)
//  - compute loop consumes slots in issue order (progressive vmcnt drain)
// ---------------------------------------------------------------------------
__global__ __launch_bounds__(1024, 4) void score_mfma(
    const ushort* __restrict__ sqb,     // [4096][256] bf16 bits
    const ushort* __restrict__ skb,     // [4096][256] bf16 bits
    const float*  __restrict__ gumbel,  // [B,H,T,T] f32
    const int*    __restrict__ mask,    // [H,T,T] int32 bool
    float* __restrict__ out)            // [B,H,T,T] f32
{
    const int tid = threadIdx.x;
    const int l   = tid & 63;
    const int w   = __builtin_amdgcn_readfirstlane(tid) >> 6;  // wave id 0..15
    const int bh  = blockIdx.x & 15;
    const int sp  = blockIdx.x >> 4;     // 0..63
    const int h   = bh & (HH - 1);
    const int b   = bh >> 3;
    const int cl  = l & 15;              // C col -> output row i offset
    const int g4  = l >> 4;              // 0..3  -> j sub-block
    const float RS = 0.17677669529663687f;  // 1/sqrt(RD)

    __shared__ float sums_lds[16][16];

    const ushort* sqbase = sqb + ((size_t)b * TT) * 256 + h * RDIM + g4 * 8;
    const ushort* skbase = skb + ((size_t)b * TT) * 256 + h * RDIM + g4 * 8;
    const float*  gb = gumbel + (size_t)bh * TT * TT;
    const int*    mb = mask + (size_t)h * TT * TT;
    float*        ob = out + (size_t)bh * TT * TT;

    #pragma unroll 1
    for (int half = 0; half < 2; ++half) {
        const int s      = half ? (127 - sp) : sp;
        const int i0     = s * 16;
        const int ntiles = s + 1;        // live 16-col tiles (max 128)
        const int zstart = ntiles * 16;
        const int i      = i0 + cl;      // this lane's output row

        // B fragment (sq row i): strip-invariant
        s8v bfrag = *(const s8v*)(sqbase + (size_t)i * 256);

        const float* grow = gb + (size_t)i * TT;
        const int*   mrow = mb + (size_t)i * TT;
        float*       orow = ob + (size_t)i * TT;

        // ---- prefetch: sk A-frags first (L2), then gumbel+mask (HBM) ----
        s8v af[8];
        f4  gv[8];
        i4  mv[8];
        #pragma unroll
        for (int it = 0; it < 4; ++it) {
            #pragma unroll
            for (int u = 0; u < 2; ++u) {
                const int sx = it * 2 + u;
                const int jt = 2 * w + it * 32 + u;
                if (jt < ntiles)
                    af[sx] = *(const s8v*)(skbase + (size_t)(jt * 16 + cl) * 256);
            }
        }
        #pragma unroll
        for (int it = 0; it < 4; ++it) {
            #pragma unroll
            for (int u = 0; u < 2; ++u) {
                const int sx = it * 2 + u;
                const int jt = 2 * w + it * 32 + u;
                if (jt < ntiles) {
                    const int jb = jt * 16 + g4 * 4;
                    gv[sx] = *(const f4*)&grow[jb];
                    mv[sx] = *(const i4*)&mrow[jb];
                }
            }
        }

        // ---- compute: consume slots in issue order ----
        float sum = 0.f;
        u2 p[4][2];
        #pragma unroll
        for (int it = 0; it < 4; ++it) {
            #pragma unroll
            for (int u = 0; u < 2; ++u) {
                const int sx = it * 2 + u;
                const int jt = 2 * w + it * 32 + u;
                if (jt < ntiles) {
                    f4 z = {0.f, 0.f, 0.f, 0.f};
                    f4 c = __builtin_amdgcn_mfma_f32_16x16x32_bf16(
                               af[sx], bfrag, z, 0, 0, 0);
                    const int jb = jt * 16 + g4 * 4;   // 4 consecutive cols
                    f4 gvv = gv[sx];
                    i4 mvv = mv[sx];
                    float e0 = (jb + 0 > i || mvv.x) ? 0.f : __expf(fmaf(c[0], RS, gvv.x));
                    float e1 = (jb + 1 > i || mvv.y) ? 0.f : __expf(fmaf(c[1], RS, gvv.y));
                    float e2 = (jb + 2 > i || mvv.z) ? 0.f : __expf(fmaf(c[2], RS, gvv.z));
                    float e3 = (jb + 3 > i || mvv.w) ? 0.f : __expf(fmaf(c[3], RS, gvv.w));
                    sum += (e0 + e1) + (e2 + e3);
                    p[it][u].x = (rnd16(e1) << 16) | rnd16(e0);
                    p[it][u].y = (rnd16(e3) << 16) | rnd16(e2);
                }
            }
        }

        // ---- row-sum reduce: across g4 groups, then across 16 waves ----
        sum += __shfl_xor(sum, 16);
        sum += __shfl_xor(sum, 32);
        if (l < 16) sums_lds[w][l] = sum;
        __syncthreads();
        float t = 0.f;
        #pragma unroll
        for (int ww = 0; ww < 16; ++ww) t += sums_lds[ww][cl];
        const float rinv = 1.0f / t;     // diagonal always live -> t > 0
        __syncthreads();                 // LDS reused by next half

        // ---- pass 2: unpack + scale + store (plain cached stores) ----
        #pragma unroll
        for (int it = 0; it < 4; ++it) {
            #pragma unroll
            for (int u = 0; u < 2; ++u) {
                const int jt = 2 * w + it * 32 + u;
                if (jt < ntiles) {
                    const int jb = jt * 16 + g4 * 4;
                    f4 v;
                    v.x = __uint_as_float(p[it][u].x << 16) * rinv;
                    v.y = __uint_as_float(p[it][u].x & 0xffff0000u) * rinv;
                    v.z = __uint_as_float(p[it][u].y << 16) * rinv;
                    v.w = __uint_as_float(p[it][u].y & 0xffff0000u) * rinv;
                    *(f4*)&orow[jb] = v;
                }
            }
        }

        // ---- zero-fill cols beyond the causal frontier ----
        for (int r = 0; r < 16; ++r) {
            for (int cz = zstart + tid * 4; cz < TT; cz += 1024 * 4) {
                f4 zz = {0.f, 0.f, 0.f, 0.f};
                *(f4*)&ob[(size_t)(i0 + r) * TT + cz] = zz;
            }
        }
    }
}

extern "C" void kernel_launch(void* const* d_in, const int* in_sizes, int n_in,
                              void* d_out, int out_size, void* d_ws, size_t ws_size,
                              hipStream_t stream) {
    const float* x      = (const float*)d_in[0];
    const int*   bmask  = (const int*)d_in[1];   // bool -> int32 per harness
    const float* gumbel = (const float*)d_in[2];
    const float* Wq     = (const float*)d_in[3];
    const float* Wk     = (const float*)d_in[4];
    float* out = (float*)d_out;

    ushort* sqb = (ushort*)d_ws;                       // 4096*256 bf16 = 2 MB
    ushort* skb = sqb + (size_t)4096 * 256;            // 2 MB
    ushort* Wt  = skb + (size_t)4096 * 256;            // 512*1024 bf16 = 1 MB

    wt_prep<<<dim3(16, 8), 256, 0, stream>>>(Wq, Wk, Wt);
    proj_mfma<<<dim3(64, 8), 256, 0, stream>>>(x, Wt, sqb, skb);

    // 16 bh x 64 balanced strip-pairs, 1024 thr (16 waves) each
    score_mfma<<<1024, 1024, 0, stream>>>(sqb, skb, gumbel, bmask, out);
}

// Round 13
// 253.031 us; speedup vs baseline: 1.0420x; 1.0420x over previous
//
#include <hip/hip_runtime.h>
#include <hip/hip_bf16.h>
#include <math.h>

// Problem constants
#define TT    2048
#define HH    8
#define RDIM  32
#define BB    2

typedef float  f4  __attribute__((ext_vector_type(4)));
typedef int    i4  __attribute__((ext_vector_type(4)));
typedef uint   u2  __attribute__((ext_vector_type(2)));
typedef uint   u4  __attribute__((ext_vector_type(4)));
typedef short  s8v __attribute__((ext_vector_type(8)));   // 8 x bf16 bits (4 VGPR)

// round-to-nearest f32 -> bf16 bits
__device__ __forceinline__ uint rnd16(float x) {
    return (__float_as_uint(x) + 0x8000u) >> 16;
}

union v8cast { u4 u; s8v s; };

// ---------------------------------------------------------------------------
// Kernel 0: Wt prep — transpose (Wq|Wk)[1024][256+256] f32 -> Wt[512][1024]
// bf16 (Wt[n][k] = W[k][n]). LDS-tiled 64x64. 1 MB output, L2-resident.
// ---------------------------------------------------------------------------
__global__ __launch_bounds__(256) void wt_prep(
    const float* __restrict__ Wq,
    const float* __restrict__ Wk,
    ushort* __restrict__ Wt)
{
    __shared__ float T[64][68];
    const int k0 = blockIdx.x * 64;
    const int n0 = blockIdx.y * 64;
    const float* W = (n0 < 256) ? Wq : Wk;
    const int nloc = n0 & 255;
    const int tid = threadIdx.x;

    #pragma unroll
    for (int r = 0; r < 4; ++r) {
        int kl  = (tid >> 4) + r * 16;
        int nl4 = (tid & 15) * 4;
        f4 v = *(const f4*)&W[(size_t)(k0 + kl) * 256 + nloc + nl4];
        T[nl4 + 0][kl] = v.x;
        T[nl4 + 1][kl] = v.y;
        T[nl4 + 2][kl] = v.z;
        T[nl4 + 3][kl] = v.w;
    }
    __syncthreads();

    const int nl = tid >> 2;
    const int kq = (tid & 3) * 16;
    u4 o0, o1;
    #pragma unroll
    for (int j = 0; j < 4; ++j) {
        uint lo = rnd16(T[nl][kq + 2 * j]);
        uint hi = rnd16(T[nl][kq + 2 * j + 1]);
        ((uint*)&o0)[j] = (hi << 16) | lo;
    }
    #pragma unroll
    for (int j = 0; j < 4; ++j) {
        uint lo = rnd16(T[nl][kq + 8 + 2 * j]);
        uint hi = rnd16(T[nl][kq + 8 + 2 * j + 1]);
        ((uint*)&o1)[j] = (hi << 16) | lo;
    }
    ushort* dst = Wt + (size_t)(n0 + nl) * 1024 + k0 + kq;
    *(u4*)dst = o0;
    *(u4*)(dst + 8) = o1;
}

// ---------------------------------------------------------------------------
// Kernel 1: MFMA projection.  sq/sk[m][n] = sum_k x[m][k] * Wt[n][k]
// mfma(A=Wt_tile, B=x_tile): D lane owns col m = lane&15, 4 consecutive n.
// ---------------------------------------------------------------------------
__global__ __launch_bounds__(256) void proj_mfma(
    const float* __restrict__ x,       // [4096][1024] f32
    const ushort* __restrict__ Wt,     // [512][1024] bf16 bits
    ushort* __restrict__ sqb,          // [4096][256] bf16 bits
    ushort* __restrict__ skb)          // [4096][256] bf16 bits
{
    const int tid = threadIdx.x;
    const int l   = tid & 63;
    const int w   = __builtin_amdgcn_readfirstlane(tid) >> 6;  // 0..3
    const int cl  = l & 15;
    const int g4  = l >> 4;
    const int m0  = (blockIdx.x * 4 + w) * 16;   // m-tile
    const int n0  = blockIdx.y * 64;             // n-block (64 wide)

    f4 acc0 = {0,0,0,0}, acc1 = {0,0,0,0}, acc2 = {0,0,0,0}, acc3 = {0,0,0,0};

    const float*  xrow = x + (size_t)(m0 + cl) * 1024;
    const ushort* wbase = Wt + (size_t)(n0 + cl) * 1024;

    for (int ks = 0; ks < 32; ++ks) {
        const int k = ks * 32 + g4 * 8;
        f4 xa = *(const f4*)&xrow[k];
        f4 xb2 = *(const f4*)&xrow[k + 4];
        v8cast bf;
        ((uint*)&bf.u)[0] = (rnd16(xa.y) << 16) | rnd16(xa.x);
        ((uint*)&bf.u)[1] = (rnd16(xa.w) << 16) | rnd16(xa.z);
        ((uint*)&bf.u)[2] = (rnd16(xb2.y) << 16) | rnd16(xb2.x);
        ((uint*)&bf.u)[3] = (rnd16(xb2.w) << 16) | rnd16(xb2.z);
        s8v a0 = *(const s8v*)(wbase + 0 * 16 * 1024 + k);
        s8v a1 = *(const s8v*)(wbase + 1 * 16 * 1024 + k);
        s8v a2 = *(const s8v*)(wbase + 2 * 16 * 1024 + k);
        s8v a3 = *(const s8v*)(wbase + 3 * 16 * 1024 + k);
        acc0 = __builtin_amdgcn_mfma_f32_16x16x32_bf16(a0, bf.s, acc0, 0, 0, 0);
        acc1 = __builtin_amdgcn_mfma_f32_16x16x32_bf16(a1, bf.s, acc1, 0, 0, 0);
        acc2 = __builtin_amdgcn_mfma_f32_16x16x32_bf16(a2, bf.s, acc2, 0, 0, 0);
        acc3 = __builtin_amdgcn_mfma_f32_16x16x32_bf16(a3, bf.s, acc3, 0, 0, 0);
    }

    const int m = m0 + cl;
    const int nbase = n0 + g4 * 4;
    ushort* obase = (n0 < 256) ? (sqb + (size_t)m * 256 + nbase)
                               : (skb + (size_t)m * 256 + (nbase - 256));
    f4 accs[4] = {acc0, acc1, acc2, acc3};
    #pragma unroll
    for (int t = 0; t < 4; ++t) {
        u2 pk;
        pk.x = (rnd16(accs[t][1]) << 16) | rnd16(accs[t][0]);
        pk.y = (rnd16(accs[t][3]) << 16) | rnd16(accs[t][2]);
        *(u2*)(obase + t * 16) = pk;
    }
}

// ---------------------------------------------------------------------------
// Kernel 2: MFMA scores + mask + gumbel + softmax (swapped operands),
// ROLLING depth-3 software pipeline (R12 lesson: prefetch-all-8 = 96 regs
// of load state -> compiler spilled at its 64-VGPR occupancy target).
//  - amdgpu_waves_per_eu(4,4): pin EXACTLY 4 waves/SIMD (one 1024-thr
//    block/CU) so the allocator gets the full 128-VGPR budget and has no
//    incentive to spill for a second block
//  - slots sx+1, sx+2 loading while slot sx computes: ~36 regs load state,
//    6 outstanding loads/wave x 16 waves/CU >> Little's-law requirement
//  - tile map jt = w + sx*16: adjacent waves cover adjacent tiles ->
//    concurrent 128B-line sharing
// ---------------------------------------------------------------------------
__global__ __attribute__((amdgpu_waves_per_eu(4, 4))) __launch_bounds__(1024)
void score_mfma(
    const ushort* __restrict__ sqb,     // [4096][256] bf16 bits
    const ushort* __restrict__ skb,     // [4096][256] bf16 bits
    const float*  __restrict__ gumbel,  // [B,H,T,T] f32
    const int*    __restrict__ mask,    // [H,T,T] int32 bool
    float* __restrict__ out)            // [B,H,T,T] f32
{
    const int tid = threadIdx.x;
    const int l   = tid & 63;
    const int w   = __builtin_amdgcn_readfirstlane(tid) >> 6;  // wave id 0..15
    const int bh  = blockIdx.x & 15;
    const int sp  = blockIdx.x >> 4;     // 0..63
    const int h   = bh & (HH - 1);
    const int b   = bh >> 3;
    const int cl  = l & 15;              // C col -> output row i offset
    const int g4  = l >> 4;              // 0..3  -> j sub-block
    const float RS = 0.17677669529663687f;  // 1/sqrt(RD)

    __shared__ float sums_lds[16][16];

    const ushort* sqbase = sqb + ((size_t)b * TT) * 256 + h * RDIM + g4 * 8;
    const ushort* skbase = skb + ((size_t)b * TT) * 256 + h * RDIM + g4 * 8;
    const float*  gb = gumbel + (size_t)bh * TT * TT;
    const int*    mb = mask + (size_t)h * TT * TT;
    float*        ob = out + (size_t)bh * TT * TT;

    #pragma unroll 1
    for (int half = 0; half < 2; ++half) {
        const int s      = half ? (127 - sp) : sp;
        const int i0     = s * 16;
        const int ntiles = s + 1;        // live 16-col tiles (max 128)
        const int zstart = ntiles * 16;
        const int i      = i0 + cl;      // this lane's output row

        // B fragment (sq row i): strip-invariant
        s8v bfrag = *(const s8v*)(sqbase + (size_t)i * 256);

        const float* grow = gb + (size_t)i * TT;
        const int*   mrow = mb + (size_t)i * TT;
        float*       orow = ob + (size_t)i * TT;

        // rolling pipeline state (static indices only; liveness-rolled)
        s8v af[8];
        f4  gv[8];
        i4  mv[8];

        #define SLOAD(sx_) do {                                               \
            const int jt_ = w + (sx_) * 16;                                   \
            if (jt_ < ntiles) {                                               \
                af[sx_] = *(const s8v*)(skbase + (size_t)(jt_ * 16 + cl) * 256); \
                const int jb_ = jt_ * 16 + g4 * 4;                            \
                gv[sx_] = *(const f4*)&grow[jb_];                             \
                mv[sx_] = *(const i4*)&mrow[jb_];                             \
            }                                                                 \
        } while (0)

        SLOAD(0);
        SLOAD(1);

        float sum = 0.f;
        u2 p[8];
        #pragma unroll
        for (int sx = 0; sx < 8; ++sx) {
            if (sx + 2 < 8) SLOAD(sx + 2);
            const int jt = w + sx * 16;
            if (jt < ntiles) {
                f4 z = {0.f, 0.f, 0.f, 0.f};
                f4 c = __builtin_amdgcn_mfma_f32_16x16x32_bf16(
                           af[sx], bfrag, z, 0, 0, 0);
                const int jb = jt * 16 + g4 * 4;   // 4 consecutive cols
                f4 gvv = gv[sx];
                i4 mvv = mv[sx];
                float e0 = (jb + 0 > i || mvv.x) ? 0.f : __expf(fmaf(c[0], RS, gvv.x));
                float e1 = (jb + 1 > i || mvv.y) ? 0.f : __expf(fmaf(c[1], RS, gvv.y));
                float e2 = (jb + 2 > i || mvv.z) ? 0.f : __expf(fmaf(c[2], RS, gvv.z));
                float e3 = (jb + 3 > i || mvv.w) ? 0.f : __expf(fmaf(c[3], RS, gvv.w));
                sum += (e0 + e1) + (e2 + e3);
                p[sx].x = (rnd16(e1) << 16) | rnd16(e0);
                p[sx].y = (rnd16(e3) << 16) | rnd16(e2);
            }
        }
        #undef SLOAD

        // ---- row-sum reduce: across g4 groups, then across 16 waves ----
        sum += __shfl_xor(sum, 16);
        sum += __shfl_xor(sum, 32);
        if (l < 16) sums_lds[w][l] = sum;
        __syncthreads();
        float t = 0.f;
        #pragma unroll
        for (int ww = 0; ww < 16; ++ww) t += sums_lds[ww][cl];
        const float rinv = 1.0f / t;     // diagonal always live -> t > 0
        __syncthreads();                 // LDS reused by next half

        // ---- pass 2: unpack + scale + store (plain cached stores) ----
        #pragma unroll
        for (int sx = 0; sx < 8; ++sx) {
            const int jt = w + sx * 16;
            if (jt < ntiles) {
                const int jb = jt * 16 + g4 * 4;
                f4 v;
                v.x = __uint_as_float(p[sx].x << 16) * rinv;
                v.y = __uint_as_float(p[sx].x & 0xffff0000u) * rinv;
                v.z = __uint_as_float(p[sx].y << 16) * rinv;
                v.w = __uint_as_float(p[sx].y & 0xffff0000u) * rinv;
                *(f4*)&orow[jb] = v;
            }
        }

        // ---- zero-fill cols beyond the causal frontier ----
        for (int r = 0; r < 16; ++r) {
            for (int cz = zstart + tid * 4; cz < TT; cz += 1024 * 4) {
                f4 zz = {0.f, 0.f, 0.f, 0.f};
                *(f4*)&ob[(size_t)(i0 + r) * TT + cz] = zz;
            }
        }
    }
}

extern "C" void kernel_launch(void* const* d_in, const int* in_sizes, int n_in,
                              void* d_out, int out_size, void* d_ws, size_t ws_size,
                              hipStream_t stream) {
    const float* x      = (const float*)d_in[0];
    const int*   bmask  = (const int*)d_in[1];   // bool -> int32 per harness
    const float* gumbel = (const float*)d_in[2];
    const float* Wq     = (const float*)d_in[3];
    const float* Wk     = (const float*)d_in[4];
    float* out = (float*)d_out;

    ushort* sqb = (ushort*)d_ws;                       // 4096*256 bf16 = 2 MB
    ushort* skb = sqb + (size_t)4096 * 256;            // 2 MB
    ushort* Wt  = skb + (size_t)4096 * 256;            // 512*1024 bf16 = 1 MB

    wt_prep<<<dim3(16, 8), 256, 0, stream>>>(Wq, Wk, Wt);
    proj_mfma<<<dim3(64, 8), 256, 0, stream>>>(x, Wt, sqb, skb);

    // 16 bh x 64 balanced strip-pairs, 1024 thr (16 waves) each
    score_mfma<<<1024, 1024, 0, stream>>>(sqb, skb, gumbel, bmask, out);
}

// Round 14
// 201.910 us; speedup vs baseline: 1.3058x; 1.2532x over previous
//
#include <hip/hip_runtime.h>
#include <hip/hip_bf16.h>
#include <math.h>

// Problem constants
#define TT    2048
#define HH    8
#define RDIM  32
#define BB    2

typedef float  f4  __attribute__((ext_vector_type(4)));
typedef int    i4  __attribute__((ext_vector_type(4)));
typedef uint   u2  __attribute__((ext_vector_type(2)));
typedef uint   u4  __attribute__((ext_vector_type(4)));
typedef short  s8v __attribute__((ext_vector_type(8)));   // 8 x bf16 bits (4 VGPR)

// round-to-nearest f32 -> bf16 bits
__device__ __forceinline__ uint rnd16(float x) {
    return (__float_as_uint(x) + 0x8000u) >> 16;
}

union v8cast { u4 u; s8v s; };

// ---------------------------------------------------------------------------
// Kernel 0: Wt prep — transpose (Wq|Wk)[1024][256+256] f32 -> Wt[512][1024]
// bf16 (Wt[n][k] = W[k][n]). LDS-tiled 64x64. 1 MB output, L2-resident.
// ---------------------------------------------------------------------------
__global__ __launch_bounds__(256) void wt_prep(
    const float* __restrict__ Wq,
    const float* __restrict__ Wk,
    ushort* __restrict__ Wt)
{
    __shared__ float T[64][68];
    const int k0 = blockIdx.x * 64;
    const int n0 = blockIdx.y * 64;
    const float* W = (n0 < 256) ? Wq : Wk;
    const int nloc = n0 & 255;
    const int tid = threadIdx.x;

    #pragma unroll
    for (int r = 0; r < 4; ++r) {
        int kl  = (tid >> 4) + r * 16;
        int nl4 = (tid & 15) * 4;
        f4 v = *(const f4*)&W[(size_t)(k0 + kl) * 256 + nloc + nl4];
        T[nl4 + 0][kl] = v.x;
        T[nl4 + 1][kl] = v.y;
        T[nl4 + 2][kl] = v.z;
        T[nl4 + 3][kl] = v.w;
    }
    __syncthreads();

    const int nl = tid >> 2;
    const int kq = (tid & 3) * 16;
    u4 o0, o1;
    #pragma unroll
    for (int j = 0; j < 4; ++j) {
        uint lo = rnd16(T[nl][kq + 2 * j]);
        uint hi = rnd16(T[nl][kq + 2 * j + 1]);
        ((uint*)&o0)[j] = (hi << 16) | lo;
    }
    #pragma unroll
    for (int j = 0; j < 4; ++j) {
        uint lo = rnd16(T[nl][kq + 8 + 2 * j]);
        uint hi = rnd16(T[nl][kq + 8 + 2 * j + 1]);
        ((uint*)&o1)[j] = (hi << 16) | lo;
    }
    ushort* dst = Wt + (size_t)(n0 + nl) * 1024 + k0 + kq;
    *(u4*)dst = o0;
    *(u4*)(dst + 8) = o1;
}

// ---------------------------------------------------------------------------
// Kernel 1: MFMA projection.  sq/sk[m][n] = sum_k x[m][k] * Wt[n][k]
// mfma(A=Wt_tile, B=x_tile): D lane owns col m = lane&15, 4 consecutive n.
// ---------------------------------------------------------------------------
__global__ __launch_bounds__(256) void proj_mfma(
    const float* __restrict__ x,       // [4096][1024] f32
    const ushort* __restrict__ Wt,     // [512][1024] bf16 bits
    ushort* __restrict__ sqb,          // [4096][256] bf16 bits
    ushort* __restrict__ skb)          // [4096][256] bf16 bits
{
    const int tid = threadIdx.x;
    const int l   = tid & 63;
    const int w   = __builtin_amdgcn_readfirstlane(tid) >> 6;  // 0..3
    const int cl  = l & 15;
    const int g4  = l >> 4;
    const int m0  = (blockIdx.x * 4 + w) * 16;   // m-tile
    const int n0  = blockIdx.y * 64;             // n-block (64 wide)

    f4 acc0 = {0,0,0,0}, acc1 = {0,0,0,0}, acc2 = {0,0,0,0}, acc3 = {0,0,0,0};

    const float*  xrow = x + (size_t)(m0 + cl) * 1024;
    const ushort* wbase = Wt + (size_t)(n0 + cl) * 1024;

    for (int ks = 0; ks < 32; ++ks) {
        const int k = ks * 32 + g4 * 8;
        f4 xa = *(const f4*)&xrow[k];
        f4 xb2 = *(const f4*)&xrow[k + 4];
        v8cast bf;
        ((uint*)&bf.u)[0] = (rnd16(xa.y) << 16) | rnd16(xa.x);
        ((uint*)&bf.u)[1] = (rnd16(xa.w) << 16) | rnd16(xa.z);
        ((uint*)&bf.u)[2] = (rnd16(xb2.y) << 16) | rnd16(xb2.x);
        ((uint*)&bf.u)[3] = (rnd16(xb2.w) << 16) | rnd16(xb2.z);
        s8v a0 = *(const s8v*)(wbase + 0 * 16 * 1024 + k);
        s8v a1 = *(const s8v*)(wbase + 1 * 16 * 1024 + k);
        s8v a2 = *(const s8v*)(wbase + 2 * 16 * 1024 + k);
        s8v a3 = *(const s8v*)(wbase + 3 * 16 * 1024 + k);
        acc0 = __builtin_amdgcn_mfma_f32_16x16x32_bf16(a0, bf.s, acc0, 0, 0, 0);
        acc1 = __builtin_amdgcn_mfma_f32_16x16x32_bf16(a1, bf.s, acc1, 0, 0, 0);
        acc2 = __builtin_amdgcn_mfma_f32_16x16x32_bf16(a2, bf.s, acc2, 0, 0, 0);
        acc3 = __builtin_amdgcn_mfma_f32_16x16x32_bf16(a3, bf.s, acc3, 0, 0, 0);
    }

    const int m = m0 + cl;
    const int nbase = n0 + g4 * 4;
    ushort* obase = (n0 < 256) ? (sqb + (size_t)m * 256 + nbase)
                               : (skb + (size_t)m * 256 + (nbase - 256));
    f4 accs[4] = {acc0, acc1, acc2, acc3};
    #pragma unroll
    for (int t = 0; t < 4; ++t) {
        u2 pk;
        pk.x = (rnd16(accs[t][1]) << 16) | rnd16(accs[t][0]);
        pk.y = (rnd16(accs[t][3]) << 16) | rnd16(accs[t][2]);
        *(u2*)(obase + t * 16) = pk;
    }
}

// ---------------------------------------------------------------------------
// Kernel 2: MFMA scores + mask + gumbel + softmax (swapped operands).
// R14: 512-thr blocks (R10's no-spill shape) + launch_bounds(512,2) to lift
// the VGPR ceiling; exp values live in LDS (p_lds, 64KB) instead of 32 VGPRs;
// explicit ping-pong pipeline one tile-PAIR ahead (static parity indices) ->
// ~6 outstanding loads/wave without spilling. Gumbel loads NT (read-once);
// zero-fill stores NT (full-line); pass-2 stores plain cached.
// ---------------------------------------------------------------------------
__global__ __launch_bounds__(512, 2) void score_mfma(
    const ushort* __restrict__ sqb,     // [4096][256] bf16 bits
    const ushort* __restrict__ skb,     // [4096][256] bf16 bits
    const float*  __restrict__ gumbel,  // [B,H,T,T] f32
    const int*    __restrict__ mask,    // [H,T,T] int32 bool
    float* __restrict__ out)            // [B,H,T,T] f32
{
    const int tid = threadIdx.x;
    const int l   = tid & 63;
    const int w   = __builtin_amdgcn_readfirstlane(tid) >> 6;  // wave id 0..7
    const int bh  = blockIdx.x & 15;
    const int sp  = blockIdx.x >> 4;     // 0..63
    const int h   = bh & (HH - 1);
    const int b   = bh >> 3;
    const int cl  = l & 15;              // C col -> output row i offset
    const int g4  = l >> 4;              // 0..3  -> j sub-block
    const float RS = 0.17677669529663687f;  // 1/sqrt(RD)

    __shared__ u2    p_lds[8][16][64];   // exp packed 2xbf16 per uint: 64 KB
    __shared__ float sums_lds[8][16];

    const ushort* sqbase = sqb + ((size_t)b * TT) * 256 + h * RDIM + g4 * 8;
    const ushort* skbase = skb + ((size_t)b * TT) * 256 + h * RDIM + g4 * 8;
    const float*  gb = gumbel + (size_t)bh * TT * TT;
    const int*    mb = mask + (size_t)h * TT * TT;
    float*        ob = out + (size_t)bh * TT * TT;

    #pragma unroll 1
    for (int half = 0; half < 2; ++half) {
        const int s      = half ? (127 - sp) : sp;
        const int i0     = s * 16;
        const int ntiles = s + 1;        // live 16-col tiles (max 128)
        const int zstart = ntiles * 16;
        const int i      = i0 + cl;      // this lane's output row

        // B fragment (sq row i): strip-invariant
        s8v bfrag = *(const s8v*)(sqbase + (size_t)i * 256);

        const float* grow = gb + (size_t)i * TT;
        const int*   mrow = mb + (size_t)i * TT;
        float*       orow = ob + (size_t)i * TT;

        // ping-pong pipeline state: one tile-pair ahead (static indices)
        s8v af[2][2];
        f4  gv[2][2];
        i4  mv[2][2];

        #define PLOAD(buf_, it_) do {                                          \
            _Pragma("unroll")                                                  \
            for (int u_ = 0; u_ < 2; ++u_) {                                   \
                const int jt_ = 2 * w + (it_) * 16 + u_;                       \
                if (jt_ < ntiles) {                                            \
                    af[buf_][u_] = *(const s8v*)(skbase +                      \
                                     (size_t)(jt_ * 16 + cl) * 256);           \
                    const int jb_ = jt_ * 16 + g4 * 4;                         \
                    gv[buf_][u_] = __builtin_nontemporal_load(                 \
                                     (const f4*)&grow[jb_]);                   \
                    mv[buf_][u_] = *(const i4*)&mrow[jb_];                     \
                }                                                              \
            }                                                                  \
        } while (0)

        PLOAD(0, 0);

        float sum = 0.f;
        #pragma unroll
        for (int it = 0; it < 8; ++it) {
            const int pb = it & 1;                 // literal per iteration
            if (it < 7) PLOAD(pb ^ 1, it + 1);     // prefetch next pair
            #pragma unroll
            for (int u = 0; u < 2; ++u) {
                const int jt = 2 * w + it * 16 + u;
                if (jt < ntiles) {
                    f4 z = {0.f, 0.f, 0.f, 0.f};
                    f4 c = __builtin_amdgcn_mfma_f32_16x16x32_bf16(
                               af[pb][u], bfrag, z, 0, 0, 0);
                    const int jb = jt * 16 + g4 * 4;   // 4 consecutive cols
                    f4 gvv = gv[pb][u];
                    i4 mvv = mv[pb][u];
                    float e0 = (jb + 0 > i || mvv.x) ? 0.f : __expf(fmaf(c[0], RS, gvv.x));
                    float e1 = (jb + 1 > i || mvv.y) ? 0.f : __expf(fmaf(c[1], RS, gvv.y));
                    float e2 = (jb + 2 > i || mvv.z) ? 0.f : __expf(fmaf(c[2], RS, gvv.z));
                    float e3 = (jb + 3 > i || mvv.w) ? 0.f : __expf(fmaf(c[3], RS, gvv.w));
                    sum += (e0 + e1) + (e2 + e3);
                    u2 pk;
                    pk.x = (rnd16(e1) << 16) | rnd16(e0);
                    pk.y = (rnd16(e3) << 16) | rnd16(e2);
                    p_lds[w][it * 2 + u][l] = pk;
                }
            }
        }
        #undef PLOAD

        // ---- row-sum reduce: across g4 groups, then across 8 waves ----
        sum += __shfl_xor(sum, 16);
        sum += __shfl_xor(sum, 32);
        if (l < 16) sums_lds[w][l] = sum;
        __syncthreads();
        float t = 0.f;
        #pragma unroll
        for (int ww = 0; ww < 8; ++ww) t += sums_lds[ww][cl];
        const float rinv = 1.0f / t;     // diagonal always live -> t > 0
        __syncthreads();                 // LDS reused by next half

        // ---- pass 2: read p from LDS, unpack + scale + store ----
        #pragma unroll
        for (int sx = 0; sx < 16; ++sx) {
            const int jt = 2 * w + (sx >> 1) * 16 + (sx & 1);
            if (jt < ntiles) {
                const int jb = jt * 16 + g4 * 4;
                u2 pk = p_lds[w][sx][l];
                f4 v;
                v.x = __uint_as_float(pk.x << 16) * rinv;
                v.y = __uint_as_float(pk.x & 0xffff0000u) * rinv;
                v.z = __uint_as_float(pk.y << 16) * rinv;
                v.w = __uint_as_float(pk.y & 0xffff0000u) * rinv;
                *(f4*)&orow[jb] = v;
            }
        }

        // ---- zero-fill cols beyond the causal frontier (full lines, NT) ----
        for (int r = 0; r < 16; ++r) {
            for (int cz = zstart + tid * 4; cz < TT; cz += 512 * 4) {
                f4 zz = {0.f, 0.f, 0.f, 0.f};
                __builtin_nontemporal_store(zz, (f4*)&ob[(size_t)(i0 + r) * TT + cz]);
            }
        }
    }
}

extern "C" void kernel_launch(void* const* d_in, const int* in_sizes, int n_in,
                              void* d_out, int out_size, void* d_ws, size_t ws_size,
                              hipStream_t stream) {
    const float* x      = (const float*)d_in[0];
    const int*   bmask  = (const int*)d_in[1];   // bool -> int32 per harness
    const float* gumbel = (const float*)d_in[2];
    const float* Wq     = (const float*)d_in[3];
    const float* Wk     = (const float*)d_in[4];
    float* out = (float*)d_out;

    ushort* sqb = (ushort*)d_ws;                       // 4096*256 bf16 = 2 MB
    ushort* skb = sqb + (size_t)4096 * 256;            // 2 MB
    ushort* Wt  = skb + (size_t)4096 * 256;            // 512*1024 bf16 = 1 MB

    wt_prep<<<dim3(16, 8), 256, 0, stream>>>(Wq, Wk, Wt);
    proj_mfma<<<dim3(64, 8), 256, 0, stream>>>(x, Wt, sqb, skb);

    // 16 bh x 64 balanced strip-pairs, 512 thr (8 waves) each
    score_mfma<<<1024, 512, 0, stream>>>(sqb, skb, gumbel, bmask, out);
}

// Round 15
// 197.424 us; speedup vs baseline: 1.3354x; 1.0227x over previous
//
#include <hip/hip_runtime.h>
#include <hip/hip_bf16.h>
#include <math.h>

// Problem constants
#define TT    2048
#define HH    8
#define RDIM  32
#define BB    2

typedef float  f4  __attribute__((ext_vector_type(4)));
typedef int    i4  __attribute__((ext_vector_type(4)));
typedef uint   u2  __attribute__((ext_vector_type(2)));
typedef uint   u4  __attribute__((ext_vector_type(4)));
typedef short  s8v __attribute__((ext_vector_type(8)));   // 8 x bf16 bits (4 VGPR)

// round-to-nearest f32 -> bf16 bits
__device__ __forceinline__ uint rnd16(float x) {
    return (__float_as_uint(x) + 0x8000u) >> 16;
}

union v8cast { u4 u; s8v s; };

// ---------------------------------------------------------------------------
// Kernel 0: Wt prep — transpose (Wq|Wk)[1024][256+256] f32 -> Wt[512][1024]
// bf16 (Wt[n][k] = W[k][n]). LDS-tiled 64x64. 1 MB output, L2-resident.
// ---------------------------------------------------------------------------
__global__ __launch_bounds__(256) void wt_prep(
    const float* __restrict__ Wq,
    const float* __restrict__ Wk,
    ushort* __restrict__ Wt)
{
    __shared__ float T[64][68];
    const int k0 = blockIdx.x * 64;
    const int n0 = blockIdx.y * 64;
    const float* W = (n0 < 256) ? Wq : Wk;
    const int nloc = n0 & 255;
    const int tid = threadIdx.x;

    #pragma unroll
    for (int r = 0; r < 4; ++r) {
        int kl  = (tid >> 4) + r * 16;
        int nl4 = (tid & 15) * 4;
        f4 v = *(const f4*)&W[(size_t)(k0 + kl) * 256 + nloc + nl4];
        T[nl4 + 0][kl] = v.x;
        T[nl4 + 1][kl] = v.y;
        T[nl4 + 2][kl] = v.z;
        T[nl4 + 3][kl] = v.w;
    }
    __syncthreads();

    const int nl = tid >> 2;
    const int kq = (tid & 3) * 16;
    u4 o0, o1;
    #pragma unroll
    for (int j = 0; j < 4; ++j) {
        uint lo = rnd16(T[nl][kq + 2 * j]);
        uint hi = rnd16(T[nl][kq + 2 * j + 1]);
        ((uint*)&o0)[j] = (hi << 16) | lo;
    }
    #pragma unroll
    for (int j = 0; j < 4; ++j) {
        uint lo = rnd16(T[nl][kq + 8 + 2 * j]);
        uint hi = rnd16(T[nl][kq + 8 + 2 * j + 1]);
        ((uint*)&o1)[j] = (hi << 16) | lo;
    }
    ushort* dst = Wt + (size_t)(n0 + nl) * 1024 + k0 + kq;
    *(u4*)dst = o0;
    *(u4*)(dst + 8) = o1;
}

// ---------------------------------------------------------------------------
// Kernel 1: MFMA projection.  sq/sk[m][n] = sum_k x[m][k] * Wt[n][k]
// mfma(A=Wt_tile, B=x_tile): D lane owns col m = lane&15, 4 consecutive n.
// ---------------------------------------------------------------------------
__global__ __launch_bounds__(256) void proj_mfma(
    const float* __restrict__ x,       // [4096][1024] f32
    const ushort* __restrict__ Wt,     // [512][1024] bf16 bits
    ushort* __restrict__ sqb,          // [4096][256] bf16 bits
    ushort* __restrict__ skb)          // [4096][256] bf16 bits
{
    const int tid = threadIdx.x;
    const int l   = tid & 63;
    const int w   = __builtin_amdgcn_readfirstlane(tid) >> 6;  // 0..3
    const int cl  = l & 15;
    const int g4  = l >> 4;
    const int m0  = (blockIdx.x * 4 + w) * 16;   // m-tile
    const int n0  = blockIdx.y * 64;             // n-block (64 wide)

    f4 acc0 = {0,0,0,0}, acc1 = {0,0,0,0}, acc2 = {0,0,0,0}, acc3 = {0,0,0,0};

    const float*  xrow = x + (size_t)(m0 + cl) * 1024;
    const ushort* wbase = Wt + (size_t)(n0 + cl) * 1024;

    for (int ks = 0; ks < 32; ++ks) {
        const int k = ks * 32 + g4 * 8;
        f4 xa = *(const f4*)&xrow[k];
        f4 xb2 = *(const f4*)&xrow[k + 4];
        v8cast bf;
        ((uint*)&bf.u)[0] = (rnd16(xa.y) << 16) | rnd16(xa.x);
        ((uint*)&bf.u)[1] = (rnd16(xa.w) << 16) | rnd16(xa.z);
        ((uint*)&bf.u)[2] = (rnd16(xb2.y) << 16) | rnd16(xb2.x);
        ((uint*)&bf.u)[3] = (rnd16(xb2.w) << 16) | rnd16(xb2.z);
        s8v a0 = *(const s8v*)(wbase + 0 * 16 * 1024 + k);
        s8v a1 = *(const s8v*)(wbase + 1 * 16 * 1024 + k);
        s8v a2 = *(const s8v*)(wbase + 2 * 16 * 1024 + k);
        s8v a3 = *(const s8v*)(wbase + 3 * 16 * 1024 + k);
        acc0 = __builtin_amdgcn_mfma_f32_16x16x32_bf16(a0, bf.s, acc0, 0, 0, 0);
        acc1 = __builtin_amdgcn_mfma_f32_16x16x32_bf16(a1, bf.s, acc1, 0, 0, 0);
        acc2 = __builtin_amdgcn_mfma_f32_16x16x32_bf16(a2, bf.s, acc2, 0, 0, 0);
        acc3 = __builtin_amdgcn_mfma_f32_16x16x32_bf16(a3, bf.s, acc3, 0, 0, 0);
    }

    const int m = m0 + cl;
    const int nbase = n0 + g4 * 4;
    ushort* obase = (n0 < 256) ? (sqb + (size_t)m * 256 + nbase)
                               : (skb + (size_t)m * 256 + (nbase - 256));
    f4 accs[4] = {acc0, acc1, acc2, acc3};
    #pragma unroll
    for (int t = 0; t < 4; ++t) {
        u2 pk;
        pk.x = (rnd16(accs[t][1]) << 16) | rnd16(accs[t][0]);
        pk.y = (rnd16(accs[t][3]) << 16) | rnd16(accs[t][2]);
        *(u2*)(obase + t * 16) = pk;
    }
}

// ---------------------------------------------------------------------------
// Kernel 2: MFMA scores + mask + gumbel + softmax (swapped operands).
// R14: 512-thr blocks (R10's no-spill shape) + launch_bounds(512,2) to lift
// the VGPR ceiling; exp values live in LDS (p_lds, 64KB) instead of 32 VGPRs;
// explicit ping-pong pipeline one tile-PAIR ahead (static parity indices) ->
// ~6 outstanding loads/wave without spilling. Gumbel loads NT (read-once);
// zero-fill stores NT (full-line); pass-2 stores plain cached.
// ---------------------------------------------------------------------------
__global__ __launch_bounds__(512, 2) void score_mfma(
    const ushort* __restrict__ sqb,     // [4096][256] bf16 bits
    const ushort* __restrict__ skb,     // [4096][256] bf16 bits
    const float*  __restrict__ gumbel,  // [B,H,T,T] f32
    const int*    __restrict__ mask,    // [H,T,T] int32 bool
    float* __restrict__ out)            // [B,H,T,T] f32
{
    const int tid = threadIdx.x;
    const int l   = tid & 63;
    const int w   = __builtin_amdgcn_readfirstlane(tid) >> 6;  // wave id 0..7
    const int bh  = blockIdx.x & 15;
    const int sp  = blockIdx.x >> 4;     // 0..63
    const int h   = bh & (HH - 1);
    const int b   = bh >> 3;
    const int cl  = l & 15;              // C col -> output row i offset
    const int g4  = l >> 4;              // 0..3  -> j sub-block
    const float RS = 0.17677669529663687f;  // 1/sqrt(RD)

    __shared__ u2    p_lds[8][16][64];   // exp packed 2xbf16 per uint: 64 KB
    __shared__ float sums_lds[8][16];

    const ushort* sqbase = sqb + ((size_t)b * TT) * 256 + h * RDIM + g4 * 8;
    const ushort* skbase = skb + ((size_t)b * TT) * 256 + h * RDIM + g4 * 8;
    const float*  gb = gumbel + (size_t)bh * TT * TT;
    const int*    mb = mask + (size_t)h * TT * TT;
    float*        ob = out + (size_t)bh * TT * TT;

    #pragma unroll 1
    for (int half = 0; half < 2; ++half) {
        const int s      = half ? (127 - sp) : sp;
        const int i0     = s * 16;
        const int ntiles = s + 1;        // live 16-col tiles (max 128)
        const int zstart = ntiles * 16;
        const int i      = i0 + cl;      // this lane's output row

        // B fragment (sq row i): strip-invariant
        s8v bfrag = *(const s8v*)(sqbase + (size_t)i * 256);

        const float* grow = gb + (size_t)i * TT;
        const int*   mrow = mb + (size_t)i * TT;
        float*       orow = ob + (size_t)i * TT;

        // ping-pong pipeline state: one tile-pair ahead (static indices)
        s8v af[2][2];
        f4  gv[2][2];
        i4  mv[2][2];

        #define PLOAD(buf_, it_) do {                                          \
            _Pragma("unroll")                                                  \
            for (int u_ = 0; u_ < 2; ++u_) {                                   \
                const int jt_ = 2 * w + (it_) * 16 + u_;                       \
                if (jt_ < ntiles) {                                            \
                    af[buf_][u_] = *(const s8v*)(skbase +                      \
                                     (size_t)(jt_ * 16 + cl) * 256);           \
                    const int jb_ = jt_ * 16 + g4 * 4;                         \
                    gv[buf_][u_] = __builtin_nontemporal_load(                 \
                                     (const f4*)&grow[jb_]);                   \
                    mv[buf_][u_] = *(const i4*)&mrow[jb_];                     \
                }                                                              \
            }                                                                  \
        } while (0)

        PLOAD(0, 0);

        float sum = 0.f;
        #pragma unroll
        for (int it = 0; it < 8; ++it) {
            const int pb = it & 1;                 // literal per iteration
            if (it < 7) PLOAD(pb ^ 1, it + 1);     // prefetch next pair
            #pragma unroll
            for (int u = 0; u < 2; ++u) {
                const int jt = 2 * w + it * 16 + u;
                if (jt < ntiles) {
                    f4 z = {0.f, 0.f, 0.f, 0.f};
                    f4 c = __builtin_amdgcn_mfma_f32_16x16x32_bf16(
                               af[pb][u], bfrag, z, 0, 0, 0);
                    const int jb = jt * 16 + g4 * 4;   // 4 consecutive cols
                    f4 gvv = gv[pb][u];
                    i4 mvv = mv[pb][u];
                    float e0 = (jb + 0 > i || mvv.x) ? 0.f : __expf(fmaf(c[0], RS, gvv.x));
                    float e1 = (jb + 1 > i || mvv.y) ? 0.f : __expf(fmaf(c[1], RS, gvv.y));
                    float e2 = (jb + 2 > i || mvv.z) ? 0.f : __expf(fmaf(c[2], RS, gvv.z));
                    float e3 = (jb + 3 > i || mvv.w) ? 0.f : __expf(fmaf(c[3], RS, gvv.w));
                    sum += (e0 + e1) + (e2 + e3);
                    u2 pk;
                    pk.x = (rnd16(e1) << 16) | rnd16(e0);
                    pk.y = (rnd16(e3) << 16) | rnd16(e2);
                    p_lds[w][it * 2 + u][l] = pk;
                }
            }
        }
        #undef PLOAD

        // ---- row-sum reduce: across g4 groups, then across 8 waves ----
        sum += __shfl_xor(sum, 16);
        sum += __shfl_xor(sum, 32);
        if (l < 16) sums_lds[w][l] = sum;
        __syncthreads();
        float t = 0.f;
        #pragma unroll
        for (int ww = 0; ww < 8; ++ww) t += sums_lds[ww][cl];
        const float rinv = 1.0f / t;     // diagonal always live -> t > 0
        __syncthreads();                 // LDS reused by next half

        // ---- pass 2: read p from LDS, unpack + scale + store ----
        #pragma unroll
        for (int sx = 0; sx < 16; ++sx) {
            const int jt = 2 * w + (sx >> 1) * 16 + (sx & 1);
            if (jt < ntiles) {
                const int jb = jt * 16 + g4 * 4;
                u2 pk = p_lds[w][sx][l];
                f4 v;
                v.x = __uint_as_float(pk.x << 16) * rinv;
                v.y = __uint_as_float(pk.x & 0xffff0000u) * rinv;
                v.z = __uint_as_float(pk.y << 16) * rinv;
                v.w = __uint_as_float(pk.y & 0xffff0000u) * rinv;
                *(f4*)&orow[jb] = v;
            }
        }

        // ---- zero-fill cols beyond the causal frontier (full lines, NT) ----
        for (int r = 0; r < 16; ++r) {
            for (int cz = zstart + tid * 4; cz < TT; cz += 512 * 4) {
                f4 zz = {0.f, 0.f, 0.f, 0.f};
                __builtin_nontemporal_store(zz, (f4*)&ob[(size_t)(i0 + r) * TT + cz]);
            }
        }
    }
}

extern "C" void kernel_launch(void* const* d_in, const int* in_sizes, int n_in,
                              void* d_out, int out_size, void* d_ws, size_t ws_size,
                              hipStream_t stream) {
    const float* x      = (const float*)d_in[0];
    const int*   bmask  = (const int*)d_in[1];   // bool -> int32 per harness
    const float* gumbel = (const float*)d_in[2];
    const float* Wq     = (const float*)d_in[3];
    const float* Wk     = (const float*)d_in[4];
    float* out = (float*)d_out;

    ushort* sqb = (ushort*)d_ws;                       // 4096*256 bf16 = 2 MB
    ushort* skb = sqb + (size_t)4096 * 256;            // 2 MB
    ushort* Wt  = skb + (size_t)4096 * 256;            // 512*1024 bf16 = 1 MB

    wt_prep<<<dim3(16, 8), 256, 0, stream>>>(Wq, Wk, Wt);
    proj_mfma<<<dim3(64, 8), 256, 0, stream>>>(x, Wt, sqb, skb);

    // 16 bh x 64 balanced strip-pairs, 512 thr (8 waves) each
    score_mfma<<<1024, 512, 0, stream>>>(sqb, skb, gumbel, bmask, out);
}